// Round 14
// baseline (9387.928 us; speedup 1.0000x reference)
//
#include <hip/hip_runtime.h>
#include <math.h>

// Problem constants (fixed by reference)
#define T   1024
#define NB  16
#define HD  512

// ws layout (float offsets)
#define OFF_BAR  0                         // 256 ints: flag[2 dir][4 bgrp][32 uslice]
#define OFF_HH   256                       // h_hist [2][T][NB][HD] = 16,777,216 floats
#define OFF_SH   (OFF_HH + 16777216)       // SH [16384][512] = 8,388,608 floats
#define OFF_SEGP (OFF_SH + 8388608)        // [16384]
#define OFF_GCTX (OFF_SEGP + 16384)        // [16][1024]
#define OFF_SEL  (OFF_GCTX + 16384)        // ints [16][12]

typedef unsigned long long u64;

__device__ __forceinline__ float sigmoidf_(float x){ return 1.0f/(1.0f + __expf(-x)); }
// fast tanh via exp2-based __expf; |err| ~1e-7, graceful saturation at +/-1
__device__ __forceinline__ float tanhf_(float x){ return 1.0f - 2.0f/(1.0f + __expf(2.0f*x)); }

// ---------------------------------------------------------------------------
// Persistent bidirectional LSTM, BATCH-STAGGERED PIPELINE.
// grid=256 wgs, block=512 (8 waves). wg -> (dir, bgrp of 4 batches, uslice of
// 16 units) = r8's proven partition; 8 sync domains of 32 wgs.
//
// KEY IDEA (r14): the 4 batches are independent recurrences. Each step is
// split into 4 SLOTS, one batch per slot. The flag for (s-1,bi) was posted 4
// slots (~1.4us of compute) before slot (s,bi) polls it -- longer than the
// store->flag->visible latency (~1us) -- so in steady state every poll hits
// on the first probe and the loop runs at COMPUTE speed, not latency speed
// (r4/r8/r10/r12 all exposed ~2.6us latency per step in lockstep).
// Duty rotation: gate wave = bi, poll wave = 4+bi (serial tails spread).
// Producer: sc1 h-store (16 x 4B = one 64B line) + flag, NO vmcnt ack --
// consumer canary-verifies its own 32B h slice (plain cached fast path,
// atomic-u64 sc1 reload fallback; r12-proven combination).
// ---------------------------------------------------------------------------
__global__ __launch_bounds__(512, 1)
void lstm_kernel(const int* __restrict__ instr, const float* __restrict__ emb,
                 const float* __restrict__ wih_f, const float* __restrict__ whh_f,
                 const float* __restrict__ bih_f, const float* __restrict__ bhh_f,
                 const float* __restrict__ wih_b, const float* __restrict__ whh_b,
                 const float* __restrict__ bih_b, const float* __restrict__ bhh_b,
                 float* __restrict__ ws)
{
    float* h_hist = ws + OFF_HH;
    int* flags = (int*)ws;            // [2][4][32]

    const int wg     = blockIdx.x;    // 0..255
    const int dir    = wg & 1;
    const int bgrp   = (wg >> 1) & 3; // batches bgrp*4..+3
    const int uslice = wg >> 3;       // 0..31
    const int U      = uslice * 16;   // 16 units per wg
    const int b0     = bgrp * 4;

    int* barf = flags + (dir*4 + bgrp)*32;

    const float* wih = dir ? wih_b : wih_f;
    const float* whh = dir ? whh_b : whh_f;
    const float* bih = dir ? bih_b : bih_f;
    const float* bhh = dir ? bhh_b : bhh_f;

    const int tid  = threadIdx.x;
    const int wid  = tid >> 6;        // 0..7
    const int lane = tid & 63;        // k-chunk id (8 k's per lane)

    // Weight slices (r8): row rgl = wid*8+ri of 64 (gate = rgl>>4, ul = rgl&15)
    float wi[64], wh[64];
#pragma unroll
    for (int ri = 0; ri < 8; ++ri){
        int rgl = wid*8 + ri;
        int gate = rgl >> 4, ul = rgl & 15;
        size_t row = (size_t)(gate*HD + U + ul) * HD + lane*8;
        float4 a0 = *(const float4*)(wih + row);
        float4 a1 = *(const float4*)(wih + row + 4);
        float4 b0v = *(const float4*)(whh + row);
        float4 b1v = *(const float4*)(whh + row + 4);
        wi[ri*8+0]=a0.x; wi[ri*8+1]=a0.y; wi[ri*8+2]=a0.z; wi[ri*8+3]=a0.w;
        wi[ri*8+4]=a1.x; wi[ri*8+5]=a1.y; wi[ri*8+6]=a1.z; wi[ri*8+7]=a1.w;
        wh[ri*8+0]=b0v.x; wh[ri*8+1]=b0v.y; wh[ri*8+2]=b0v.z; wh[ri*8+3]=b0v.w;
        wh[ri*8+4]=b1v.x; wh[ri*8+5]=b1v.y; wh[ri*8+6]=b1v.z; wh[ri*8+7]=b1v.w;
    }

    // Gate biases (lanes 0..15 meaningful; same for all waves)
    float bI, bF, bG, bO, cst = 0.0f;   // cst: wave w (<4) holds c for batch b0+w
    {
        int u = lane & 15;
        bI = bih[0*HD + U + u] + bhh[0*HD + U + u];
        bF = bih[1*HD + U + u] + bhh[1*HD + U + u];
        bG = bih[2*HD + U + u] + bhh[2*HD + U + u];
        bO = bih[3*HD + U + u] + bhh[3*HD + U + u];
    }

    __shared__ float gbuf[64];        // [row rgl] = [gate*16 + ul]

    // reduce ownership: lanes 0..7 write row = wid*8 + bitrev3(lane)
    const int jown3 = ((lane&1)<<2) | (lane&2) | ((lane&4)>>2);

    // x prefetch banks: xq[bank][2] float4 (8 floats = this lane's k slice)
    float4 xq[2][2];
    {
        int t0 = dir ? (T-1) : 0;
        int idx = instr[(b0+0)*T + t0];
        const float* px = emb + (size_t)idx*HD + lane*8;
        xq[0][0] = *(const float4*)px;
        xq[0][1] = *(const float4*)(px + 4);
    }

    for (int s = 0; s < T; ++s){
        const int tp  = dir ? (T-1-s) : s;
        const int tpn = dir ? (T-2-s) : (s+1);
        const int tprev = dir ? (tp+1) : (tp-1);

#pragma unroll
        for (int bi = 0; bi < 4; ++bi){
            const int cur = bi & 1, nxt = (bi+1) & 1;
            const int bN = (bi+1) & 3;
            const int tN = (bi < 3) ? tp : tpn;
            const bool haveN = (bi < 3) || (s+1 < T);

            // ---- 1. poll (wave 4+bi): flags from 4 slots ago -> first-probe hit
            if (s > 0 && wid == 4+bi){
                const int tgt = s*4 + bi - 3;   // = (s-1)*4 + bi + 1
                for (;;){
                    int v = (lane < 32)
                        ? __hip_atomic_load(barf + lane, __ATOMIC_RELAXED, __HIP_MEMORY_SCOPE_AGENT)
                        : 0x7fffffff;
                    if (__all(v >= tgt)) break;
                    __builtin_amdgcn_s_sleep(1);
                }
            }
            __syncthreads();

            // ---- 2. issue h-load (plain cached; latency hides under x-proj)
            float4 hq0, hq1;
            const float* hb = h_hist + ((size_t)(dir*T + tprev)*NB + b0 + bi)*HD + lane*8;
            if (s > 0){
                hq0 = *(const float4*)hb;
                hq1 = *(const float4*)(hb + 4);
            }

            // ---- 3. issue x prefetch for next slot
            if (haveN){
                int idx = instr[(b0+bN)*T + tN];
                const float* px = emb + (size_t)idx*HD + lane*8;
                xq[nxt][0] = *(const float4*)px;
                xq[nxt][1] = *(const float4*)(px + 4);
            }

            // ---- 4. x-proj from current bank
            float a[8];
#pragma unroll
            for (int j = 0; j < 8; ++j) a[j] = 0.0f;
            {
                float xs[8] = {xq[cur][0].x,xq[cur][0].y,xq[cur][0].z,xq[cur][0].w,
                               xq[cur][1].x,xq[cur][1].y,xq[cur][1].z,xq[cur][1].w};
#pragma unroll
                for (int kk = 0; kk < 8; ++kk){
                    float xv = xs[kk];
#pragma unroll
                    for (int ri = 0; ri < 8; ++ri)
                        a[ri] = fmaf(xv, wi[ri*8+kk], a[ri]);
                }
            }

            // ---- 5. canary-verify h, then h-proj
            if (s > 0){
                unsigned ok = 1u;
                ok &= (__float_as_uint(hq0.x)!=0xFFFFFFFFu); ok &= (__float_as_uint(hq0.y)!=0xFFFFFFFFu);
                ok &= (__float_as_uint(hq0.z)!=0xFFFFFFFFu); ok &= (__float_as_uint(hq0.w)!=0xFFFFFFFFu);
                ok &= (__float_as_uint(hq1.x)!=0xFFFFFFFFu); ok &= (__float_as_uint(hq1.y)!=0xFFFFFFFFu);
                ok &= (__float_as_uint(hq1.z)!=0xFFFFFFFFu); ok &= (__float_as_uint(hq1.w)!=0xFFFFFFFFu);
                while (!__all(ok != 0u)){
                    const u64* p = (const u64*)hb;
                    u64 q0 = __hip_atomic_load(p+0, __ATOMIC_RELAXED, __HIP_MEMORY_SCOPE_AGENT);
                    u64 q1 = __hip_atomic_load(p+1, __ATOMIC_RELAXED, __HIP_MEMORY_SCOPE_AGENT);
                    u64 q2 = __hip_atomic_load(p+2, __ATOMIC_RELAXED, __HIP_MEMORY_SCOPE_AGENT);
                    u64 q3 = __hip_atomic_load(p+3, __ATOMIC_RELAXED, __HIP_MEMORY_SCOPE_AGENT);
                    float2 f0 = __builtin_bit_cast(float2, q0);
                    float2 f1 = __builtin_bit_cast(float2, q1);
                    float2 f2 = __builtin_bit_cast(float2, q2);
                    float2 f3 = __builtin_bit_cast(float2, q3);
                    hq0 = make_float4(f0.x,f0.y,f1.x,f1.y);
                    hq1 = make_float4(f2.x,f2.y,f3.x,f3.y);
                    ok = 1u;
                    ok &= (__float_as_uint(hq0.x)!=0xFFFFFFFFu); ok &= (__float_as_uint(hq0.y)!=0xFFFFFFFFu);
                    ok &= (__float_as_uint(hq0.z)!=0xFFFFFFFFu); ok &= (__float_as_uint(hq0.w)!=0xFFFFFFFFu);
                    ok &= (__float_as_uint(hq1.x)!=0xFFFFFFFFu); ok &= (__float_as_uint(hq1.y)!=0xFFFFFFFFu);
                    ok &= (__float_as_uint(hq1.z)!=0xFFFFFFFFu); ok &= (__float_as_uint(hq1.w)!=0xFFFFFFFFu);
                }
                float hs[8] = {hq0.x,hq0.y,hq0.z,hq0.w,hq1.x,hq1.y,hq1.z,hq1.w};
#pragma unroll
                for (int kk = 0; kk < 8; ++kk){
                    float hv = hs[kk];
#pragma unroll
                    for (int ri = 0; ri < 8; ++ri)
                        a[ri] = fmaf(hv, wh[ri*8+kk], a[ri]);
                }
            }

            // ---- 6. reduce-scatter 8 values over 64 lanes (3 stages + 3 folds)
#pragma unroll
            for (int m = 0; m < 3; ++m){
                const int half = 4 >> m;
                const bool up = (lane >> m) & 1;
#pragma unroll
                for (int j = 0; j < 4; ++j){
                    if (j < half){
                        float lo = a[j], hi = a[j+half];
                        float rlo = __shfl_xor(lo, 1<<m, 64);
                        float rhi = __shfl_xor(hi, 1<<m, 64);
                        a[j] = up ? (hi + rhi) : (lo + rlo);
                    }
                }
            }
            a[0] += __shfl_xor(a[0], 8, 64);
            a[0] += __shfl_xor(a[0], 16, 64);
            a[0] += __shfl_xor(a[0], 32, 64);

            if (lane < 8) gbuf[wid*8 + jown3] = a[0];
            __syncthreads();

            // ---- 7. gates + h-store + flag (wave bi only; c-state lives there)
            if (wid == bi){
                if (lane < 16){
                    float iv = sigmoidf_(gbuf[      lane] + bI);
                    float fv = sigmoidf_(gbuf[ 16 + lane] + bF);
                    float gv = tanhf_  (gbuf[ 32 + lane] + bG);
                    float ov = sigmoidf_(gbuf[ 48 + lane] + bO);
                    cst = fv*cst + iv*gv;
                    float hv = ov * tanhf_(cst);
                    // one contiguous 64B line (16 x 4B sc1 stores)
                    __hip_atomic_store(&h_hist[((size_t)(dir*T + tp)*NB + b0 + bi)*HD + U + lane], hv,
                                       __ATOMIC_RELAXED, __HIP_MEMORY_SCOPE_AGENT);
                }
                if (lane == 0)   // no ack: canary on data covers arrival races
                    __hip_atomic_store(barf + uslice, s*4 + bi + 1,
                                       __ATOMIC_RELAXED, __HIP_MEMORY_SCOPE_AGENT);
            }
        }
    }
}

// ---------------------------------------------------------------------------
// SH = relu(enc @ ws1.T + bs1)   M=16384 N=512 K=1024, fp32 64x64x16 tiles
// ---------------------------------------------------------------------------
__global__ __launch_bounds__(256, 2)
void seg_gemm(const float* __restrict__ ws_, const float* __restrict__ ws1,
              const float* __restrict__ bs1)
{
    const float* h_hist = ws_ + OFF_HH;
    float* SH = (float*)(ws_ + OFF_SH);
    __shared__ float As[64][17];
    __shared__ float Bs[64][17];
    const int m0 = blockIdx.x * 64;
    const int n0 = blockIdx.y * 64;
    const int tid = threadIdx.x;
    const int r  = tid >> 2;
    const int kq = (tid & 3) * 4;
    const int ty = tid >> 4, tx = tid & 15;
    const int bI = m0 >> 10;          // tile stays inside one batch
    const int t0 = m0 & 1023;

    float acc[4][4];
#pragma unroll
    for (int i=0;i<4;i++)
#pragma unroll
        for (int j=0;j<4;j++) acc[i][j]=0.0f;

    for (int kb = 0; kb < 1024; kb += 16){
        int kk = kb + kq;
        const float* ap = (kk < 512)
            ? h_hist + ((size_t)(t0 + r)*NB + bI)*HD + kk
            : h_hist + ((size_t)(T + t0 + r)*NB + bI)*HD + (kk - 512);
        float4 av = *(const float4*)ap;
        As[r][kq+0]=av.x; As[r][kq+1]=av.y; As[r][kq+2]=av.z; As[r][kq+3]=av.w;
        float4 bv = *(const float4*)(ws1 + (size_t)(n0 + r)*1024 + kk);
        Bs[r][kq+0]=bv.x; Bs[r][kq+1]=bv.y; Bs[r][kq+2]=bv.z; Bs[r][kq+3]=bv.w;
        __syncthreads();
#pragma unroll
        for (int k2 = 0; k2 < 16; ++k2){
            float av_[4], bv_[4];
#pragma unroll
            for (int i=0;i<4;i++) av_[i] = As[ty*4+i][k2];
#pragma unroll
            for (int j=0;j<4;j++) bv_[j] = Bs[tx*4+j][k2];
#pragma unroll
            for (int i=0;i<4;i++)
#pragma unroll
                for (int j=0;j<4;j++) acc[i][j] = fmaf(av_[i], bv_[j], acc[i][j]);
        }
        __syncthreads();
    }
#pragma unroll
    for (int i=0;i<4;i++){
        int m = m0 + ty*4 + i;
#pragma unroll
        for (int j=0;j<4;j++){
            int n = n0 + tx*4 + j;
            SH[(size_t)m*512 + n] = fmaxf(acc[i][j] + bs1[n], 0.0f);
        }
    }
}

// ---------------------------------------------------------------------------
// scores -> sigmoid -> seg_probs (ws copy + d_out)
// ---------------------------------------------------------------------------
__global__ void seg_score(const float* __restrict__ ws_, const float* __restrict__ ws2,
                          const float* __restrict__ bs2, float* __restrict__ dout)
{
    const float* SH = ws_ + OFF_SH;
    float* segp = (float*)(ws_ + OFF_SEGP);
    int row  = blockIdx.x*4 + (threadIdx.x >> 6);
    int lane = threadIdx.x & 63;
    const float* p = SH + (size_t)row*512 + lane*8;
    const float* q = ws2 + lane*8;
    float4 a0=*(const float4*)p, a1=*(const float4*)(p+4);
    float4 b0=*(const float4*)q, b1=*(const float4*)(q+4);
    float ssum = a0.x*b0.x + a0.y*b0.y + a0.z*b0.z + a0.w*b0.w
               + a1.x*b1.x + a1.y*b1.y + a1.z*b1.z + a1.w*b1.w;
#pragma unroll
    for (int m=1;m<64;m<<=1) ssum += __shfl_xor(ssum, m, 64);
    if (lane == 0){
        float z = ssum + bs2[0];
        float pr = 1.0f/(1.0f + __expf(-z));
        segp[row] = pr;
        dout[81920 + row] = pr;
    }
}

// ---------------------------------------------------------------------------
// Per-batch: mask scan (count, first-10 idx), pooled -> gctx
// ---------------------------------------------------------------------------
__global__ void select_gctx(float* __restrict__ ws_, const float* __restrict__ wgm,
                            const float* __restrict__ bgv)
{
    const float* h_hist = ws_ + OFF_HH;
    const float* segp   = ws_ + OFF_SEGP;
    float* gctx = ws_ + OFF_GCTX;
    int* sel = (int*)(ws_ + OFF_SEL);
    int b = blockIdx.x, tid = threadIdx.x;
    __shared__ unsigned char flag[1024];
    __shared__ float pool[1024];
    for (int j = tid; j < 1024; j += 256){
        flag[j] = segp[b*1024 + j] > 0.5f ? 1 : 0;
        pool[j] = (j < 512) ? h_hist[((size_t)1023*NB + b)*HD + j]
                            : h_hist[((size_t)T*NB + b)*HD + (j - 512)];
    }
    __syncthreads();
    if (tid == 0){
        int c = 0;
        int tmp[10];
        for (int j = 0; j < 10; ++j) tmp[j] = 0;
        for (int t = 0; t < 1024; ++t){
            if (flag[t]){ if (c < 10) tmp[c] = t; c++; }
        }
        for (int j = 0; j < 10; ++j) sel[b*12 + j] = tmp[j];
        sel[b*12 + 10] = c;
        sel[b*12 + 11] = 0;
    }
    __syncthreads();
    for (int n = tid; n < 1024; n += 256){
        float acc = bgv[n];
        const float* wr = wgm + (size_t)n*1024;
        for (int k = 0; k < 1024; k += 4){
            acc += wr[k]*pool[k] + wr[k+1]*pool[k+1] + wr[k+2]*pool[k+2] + wr[k+3]*pool[k+3];
        }
        gctx[b*1024 + n] = acc;
    }
}

// ---------------------------------------------------------------------------
// Decoder: one block per (b,slot)
// ---------------------------------------------------------------------------
__global__ void decode(const float* __restrict__ ws_, const float* __restrict__ wd1,
                       const float* __restrict__ bd1, const float* __restrict__ wd2,
                       const float* __restrict__ bd2, float* __restrict__ dout)
{
    const float* h_hist = ws_ + OFF_HH;
    const float* gctx   = ws_ + OFF_GCTX;
    const int* sel = (const int*)(ws_ + OFF_SEL);
    int blk = blockIdx.x;
    int b = blk / 10, slot = blk % 10;
    int tid = threadIdx.x;
    int count = sel[b*12 + 10];
    int nval = count < 10 ? count : 10;
    bool empty = (count == 0);
    float* outp = dout + (size_t)(b*10 + slot)*512;
    if (slot >= nval && !(empty && slot == 0)){
        for (int n = tid; n < 512; n += 256) outp[n] = 0.0f;
        return;
    }
    __shared__ float row[1024];
    __shared__ float dh[512];
    if (empty){
        for (int j = tid; j < 1024; j += 256) row[j] = gctx[b*1024 + j];
    } else {
        int t = sel[b*12 + slot];
        for (int j = tid; j < 1024; j += 256)
            row[j] = (j < 512) ? h_hist[((size_t)t*NB + b)*HD + j]
                               : h_hist[((size_t)(T + t)*NB + b)*HD + (j-512)];
    }
    __syncthreads();
    for (int d = tid; d < 512; d += 256){
        float acc = bd1[d];
        const float* wr = wd1 + (size_t)d*1024;
        for (int k = 0; k < 1024; ++k) acc += wr[k]*row[k];
        dh[d] = fmaxf(acc, 0.0f);
    }
    __syncthreads();
    for (int n = tid; n < 512; n += 256){
        float acc = bd2[n];
        const float* wr = wd2 + (size_t)n*512;
        for (int k = 0; k < 512; ++k) acc += wr[k]*dh[k];
        outp[n] = acc;
    }
}

extern "C" void kernel_launch(void* const* d_in, const int* in_sizes, int n_in,
                              void* d_out, int out_size, void* d_ws, size_t ws_size,
                              hipStream_t stream)
{
    const int*   instr = (const int*)d_in[0];
    const float* emb   = (const float*)d_in[1];
    const float* wih_f = (const float*)d_in[2];
    const float* whh_f = (const float*)d_in[3];
    const float* bih_f = (const float*)d_in[4];
    const float* bhh_f = (const float*)d_in[5];
    const float* wih_b = (const float*)d_in[6];
    const float* whh_b = (const float*)d_in[7];
    const float* bih_b = (const float*)d_in[8];
    const float* bhh_b = (const float*)d_in[9];
    const float* wg_   = (const float*)d_in[10];
    const float* bg_   = (const float*)d_in[11];
    const float* ws1   = (const float*)d_in[12];
    const float* bs1   = (const float*)d_in[13];
    const float* ws2   = (const float*)d_in[14];
    const float* bs2   = (const float*)d_in[15];
    const float* wd1   = (const float*)d_in[16];
    const float* bd1   = (const float*)d_in[17];
    const float* wd2   = (const float*)d_in[18];
    const float* bd2   = (const float*)d_in[19];
    float* out = (float*)d_out;
    float* ws  = (float*)d_ws;

    // zero the flags + canary-arm the h exchange buffer (re-arms every replay)
    hipMemsetAsync(d_ws, 0, 1024, stream);
    hipMemsetAsync((char*)d_ws + (size_t)OFF_HH*4, 0xFF, (size_t)16777216*4, stream);

    hipLaunchKernelGGL(lstm_kernel, dim3(256), dim3(512), 0, stream,
                       instr, emb, wih_f, whh_f, bih_f, bhh_f,
                       wih_b, whh_b, bih_b, bhh_b, ws);
    hipLaunchKernelGGL(seg_gemm, dim3(256, 8), dim3(256), 0, stream, ws, ws1, bs1);
    hipLaunchKernelGGL(seg_score, dim3(4096), dim3(256), 0, stream, ws, ws2, bs2, out);
    hipLaunchKernelGGL(select_gctx, dim3(16), dim3(256), 0, stream, ws, wg_, bg_);
    hipLaunchKernelGGL(decode, dim3(160), dim3(256), 0, stream, ws, wd1, bd1, wd2, bd2, out);
}

// Round 15
// 4420.916 us; speedup vs baseline: 2.1235x; 2.1235x over previous
//
#include <hip/hip_runtime.h>
#include <math.h>

// Problem constants (fixed by reference)
#define T   1024
#define NB  16
#define HD  512

// ws layout (float offsets)
#define OFF_BAR  0                         // 512 ints: flag[2 dir][4 bgrp][64 uslice]
#define OFF_HH   768                       // h_hist [2][T][NB][HD] = 16,777,216 floats
#define OFF_SH   (OFF_HH + 16777216)       // SH [16384][512] = 8,388,608 floats
#define OFF_SEGP (OFF_SH + 8388608)        // [16384]
#define OFF_GCTX (OFF_SEGP + 16384)        // [16][1024]
#define OFF_SEL  (OFF_GCTX + 16384)        // ints [16][12]

typedef unsigned long long u64;

__device__ __forceinline__ float sigmoidf_(float x){ return 1.0f/(1.0f + __expf(-x)); }
// fast tanh via exp2-based __expf; |err| ~1e-7, graceful saturation at +/-1
__device__ __forceinline__ float tanhf_(float x){ return 1.0f - 2.0f/(1.0f + __expf(2.0f*x)); }

// ---------------------------------------------------------------------------
// Persistent bidirectional LSTM, TWO INDEPENDENT WGS PER CU (hardware TLP).
// grid=512, block=256 (4 waves). dir = wg>>8 -> blocks 0..255 fwd, 256..511
// bwd; round-robin placement pairs one fwd + one bwd wg per CU. The two wgs
// share NOTHING (separate barriers, separate flag arrays): when one parks in
// poll s_sleep / barrier-wait, the other's 4 waves own all 4 SIMDs -> each
// chain's ~2.6us exposed exchange latency fills with the partner chain's
// compute. This is the overlap r11/r14's software phase-splitting could not
// produce (block-wide barriers serialize phases). Worst-case placement
// (same-dir pair) degrades to r8's lockstep, not below it.
// wg -> (dir, bgrp = 4 batches, uslice = 8 units); domains = (dir,bgrp),
// 8 domains x 64 wgs. Protocol = r8 verbatim (proven): sc1 h-store ->
// vmcnt(0) -> per-wg flag; wave0 polls 64 flags (1/lane); plain cached
// h reads (fresh address per step); gbuf + 2 barriers; wave0 gates.
// ---------------------------------------------------------------------------
__global__ __launch_bounds__(256, 2)
void lstm_kernel(const int* __restrict__ instr, const float* __restrict__ emb,
                 const float* __restrict__ wih_f, const float* __restrict__ whh_f,
                 const float* __restrict__ bih_f, const float* __restrict__ bhh_f,
                 const float* __restrict__ wih_b, const float* __restrict__ whh_b,
                 const float* __restrict__ bih_b, const float* __restrict__ bhh_b,
                 float* __restrict__ ws)
{
    float* h_hist = ws + OFF_HH;
    int* flags = (int*)ws;            // [2][4][64]

    const int wg     = blockIdx.x;    // 0..511
    const int dir    = wg >> 8;       // 0 = fwd (blocks 0..255), 1 = bwd
    const int rem    = wg & 255;
    const int bgrp   = rem & 3;       // batches bgrp*4..+3
    const int uslice = rem >> 2;      // 0..63
    const int U      = uslice * 8;    // 8 hidden units per wg
    const int b0     = bgrp * 4;

    int* barf = flags + (dir*4 + bgrp)*64;

    const float* wih = dir ? wih_b : wih_f;
    const float* whh = dir ? whh_b : whh_f;
    const float* bih = dir ? bih_b : bih_f;
    const float* bhh = dir ? bhh_b : bhh_f;

    const int tid  = threadIdx.x;
    const int wid  = tid >> 6;        // 0..3 = row-group
    const int lane = tid & 63;        // k-chunk id (8 k's per lane)

    // Weight slices: row rgl = wid*8+ri of 32 (gate = rgl>>3, ul = rgl&7)
    float wi[64], wh[64];
#pragma unroll
    for (int ri = 0; ri < 8; ++ri){
        int rgl = wid*8 + ri;
        int gate = rgl >> 3, ul = rgl & 7;
        size_t row = (size_t)(gate*HD + U + ul) * HD + lane*8;
        float4 a0 = *(const float4*)(wih + row);
        float4 a1 = *(const float4*)(wih + row + 4);
        float4 b0v = *(const float4*)(whh + row);
        float4 b1v = *(const float4*)(whh + row + 4);
        wi[ri*8+0]=a0.x; wi[ri*8+1]=a0.y; wi[ri*8+2]=a0.z; wi[ri*8+3]=a0.w;
        wi[ri*8+4]=a1.x; wi[ri*8+5]=a1.y; wi[ri*8+6]=a1.z; wi[ri*8+7]=a1.w;
        wh[ri*8+0]=b0v.x; wh[ri*8+1]=b0v.y; wh[ri*8+2]=b0v.z; wh[ri*8+3]=b0v.w;
        wh[ri*8+4]=b1v.x; wh[ri*8+5]=b1v.y; wh[ri*8+6]=b1v.z; wh[ri*8+7]=b1v.w;
    }

    // Gate biases: wave0 lane M (<32) owns (b = b0+(M>>3), unit = U+(M&7))
    float bI, bF, bG, bO, cst = 0.0f;
    {
        int u = tid & 7;
        bI = bih[0*HD + U + u] + bhh[0*HD + U + u];
        bF = bih[1*HD + U + u] + bhh[1*HD + U + u];
        bG = bih[2*HD + U + u] + bhh[2*HD + U + u];
        bO = bih[3*HD + U + u] + bhh[3*HD + U + u];
    }

    __shared__ float gbuf[128];       // [gate][bi*8 + ul]

    // reduce-scatter ownership (32 values, 5 xor stages + cross-half merge):
    // lane ends holding flat j = bitrev5(lane&31); j = bi*8 + local-row(3b)
    const int jown = ((lane&1)<<4)|((lane&2)<<2)|(lane&4)|((lane&8)>>2)|((lane&16)>>4);
    const int own_bi  = jown >> 3;            // 0..3
    const int own_rgl = wid*8 + (jown & 7);   // 0..31
    const int gslot   = (own_rgl >> 3)*32 + own_bi*8 + (own_rgl & 7);

    for (int s = 0; s < T; ++s){
        const int tp = dir ? (T-1-s) : s;   // original-time index

        // ---- x gather + x-projection: independent of the recurrence
        float a[32];
#pragma unroll
        for (int j = 0; j < 32; ++j) a[j] = 0.0f;

#pragma unroll
        for (int bi = 0; bi < 4; ++bi){
            int b = b0 + bi;
            int idx = instr[b*T + tp];
            const float* px = emb + (size_t)idx*HD + lane*8;
            float4 x0 = *(const float4*)px;
            float4 x1 = *(const float4*)(px + 4);
            float xs[8] = {x0.x,x0.y,x0.z,x0.w,x1.x,x1.y,x1.z,x1.w};
#pragma unroll
            for (int kk = 0; kk < 8; ++kk){
                float xv = xs[kk];
#pragma unroll
                for (int ri = 0; ri < 8; ++ri)
                    a[bi*8+ri] = fmaf(xv, wi[ri*8+kk], a[bi*8+ri]);
            }
        }

        // ---- wait for step s-1 of the 64 wgs in this (dir,bgrp) domain
        if (s > 0){
            if (wid == 0){
                for (;;){
                    int v = __hip_atomic_load(barf + lane, __ATOMIC_RELAXED, __HIP_MEMORY_SCOPE_AGENT);
                    if (__all(v >= s)) break;
                    __builtin_amdgcn_s_sleep(1);
                }
            }
            __syncthreads();

            // ---- h-projection: plain cached loads (fresh address per step)
            const int tprev = dir ? (T - s) : (s - 1);
            const float* hbase = h_hist + (size_t)(dir*T + tprev)*NB*HD;
#pragma unroll
            for (int bi = 0; bi < 4; ++bi){
                const float* ph = hbase + (size_t)(b0+bi)*HD + lane*8;
                float4 h0 = *(const float4*)ph;
                float4 h1 = *(const float4*)(ph + 4);
                float hs[8] = {h0.x,h0.y,h0.z,h0.w,h1.x,h1.y,h1.z,h1.w};
#pragma unroll
                for (int kk = 0; kk < 8; ++kk){
                    float hv = hs[kk];
#pragma unroll
                    for (int ri = 0; ri < 8; ++ri)
                        a[bi*8+ri] = fmaf(hv, wh[ri*8+kk], a[bi*8+ri]);
                }
            }
        }

        // ---- reduce-scatter: 32 values over 64 lanes (5 stages + merge)
#pragma unroll
        for (int m = 0; m < 5; ++m){
            const int half = 16 >> m;
            const bool up = (lane >> m) & 1;
#pragma unroll
            for (int j = 0; j < 16; ++j){
                if (j < half){
                    float lo = a[j], hi = a[j+half];
                    float rlo = __shfl_xor(lo, 1<<m, 64);
                    float rhi = __shfl_xor(hi, 1<<m, 64);
                    a[j] = up ? (hi + rhi) : (lo + rlo);
                }
            }
        }
        a[0] += __shfl_xor(a[0], 32, 64);   // cross-half k merge

        if ((lane & 32) == 0) gbuf[gslot] = a[0];
        __syncthreads();

        if (tid < 32){   // wave-uniform branch: wave0 only
            float iv = sigmoidf_(gbuf[      tid] + bI);
            float fv = sigmoidf_(gbuf[ 32 + tid] + bF);
            float gv = tanhf_  (gbuf[ 64 + tid] + bG);
            float ov = sigmoidf_(gbuf[ 96 + tid] + bO);
            cst = fv*cst + iv*gv;
            float hv = ov * tanhf_(cst);
            int b = b0 + (tid >> 3), u = tid & 7;
            // sc1 store: 8 contiguous floats per batch (32B), 4 chunks/wg
            __hip_atomic_store(&h_hist[((size_t)(dir*T + tp)*NB + b)*HD + U + u], hv,
                               __ATOMIC_RELAXED, __HIP_MEMORY_SCOPE_AGENT);
        }
        // order: h stores acked at LLC before flag store; no L2 flushes
        asm volatile("s_waitcnt vmcnt(0)" ::: "memory");
        __builtin_amdgcn_sched_barrier(0);
        if (tid == 0)
            __hip_atomic_store(barf + uslice, s + 1, __ATOMIC_RELAXED, __HIP_MEMORY_SCOPE_AGENT);
        // no trailing barrier: gbuf WAR for s+1 ordered by post-poll barrier
    }
}

// ---------------------------------------------------------------------------
// SH = relu(enc @ ws1.T + bs1)   M=16384 N=512 K=1024, fp32 64x64x16 tiles
// ---------------------------------------------------------------------------
__global__ __launch_bounds__(256, 2)
void seg_gemm(const float* __restrict__ ws_, const float* __restrict__ ws1,
              const float* __restrict__ bs1)
{
    const float* h_hist = ws_ + OFF_HH;
    float* SH = (float*)(ws_ + OFF_SH);
    __shared__ float As[64][17];
    __shared__ float Bs[64][17];
    const int m0 = blockIdx.x * 64;
    const int n0 = blockIdx.y * 64;
    const int tid = threadIdx.x;
    const int r  = tid >> 2;
    const int kq = (tid & 3) * 4;
    const int ty = tid >> 4, tx = tid & 15;
    const int bI = m0 >> 10;          // tile stays inside one batch
    const int t0 = m0 & 1023;

    float acc[4][4];
#pragma unroll
    for (int i=0;i<4;i++)
#pragma unroll
        for (int j=0;j<4;j++) acc[i][j]=0.0f;

    for (int kb = 0; kb < 1024; kb += 16){
        int kk = kb + kq;
        const float* ap = (kk < 512)
            ? h_hist + ((size_t)(t0 + r)*NB + bI)*HD + kk
            : h_hist + ((size_t)(T + t0 + r)*NB + bI)*HD + (kk - 512);
        float4 av = *(const float4*)ap;
        As[r][kq+0]=av.x; As[r][kq+1]=av.y; As[r][kq+2]=av.z; As[r][kq+3]=av.w;
        float4 bv = *(const float4*)(ws1 + (size_t)(n0 + r)*1024 + kk);
        Bs[r][kq+0]=bv.x; Bs[r][kq+1]=bv.y; Bs[r][kq+2]=bv.z; Bs[r][kq+3]=bv.w;
        __syncthreads();
#pragma unroll
        for (int k2 = 0; k2 < 16; ++k2){
            float av_[4], bv_[4];
#pragma unroll
            for (int i=0;i<4;i++) av_[i] = As[ty*4+i][k2];
#pragma unroll
            for (int j=0;j<4;j++) bv_[j] = Bs[tx*4+j][k2];
#pragma unroll
            for (int i=0;i<4;i++)
#pragma unroll
                for (int j=0;j<4;j++) acc[i][j] = fmaf(av_[i], bv_[j], acc[i][j]);
        }
        __syncthreads();
    }
#pragma unroll
    for (int i=0;i<4;i++){
        int m = m0 + ty*4 + i;
#pragma unroll
        for (int j=0;j<4;j++){
            int n = n0 + tx*4 + j;
            SH[(size_t)m*512 + n] = fmaxf(acc[i][j] + bs1[n], 0.0f);
        }
    }
}

// ---------------------------------------------------------------------------
// scores -> sigmoid -> seg_probs (ws copy + d_out)
// ---------------------------------------------------------------------------
__global__ void seg_score(const float* __restrict__ ws_, const float* __restrict__ ws2,
                          const float* __restrict__ bs2, float* __restrict__ dout)
{
    const float* SH = ws_ + OFF_SH;
    float* segp = (float*)(ws_ + OFF_SEGP);
    int row  = blockIdx.x*4 + (threadIdx.x >> 6);
    int lane = threadIdx.x & 63;
    const float* p = SH + (size_t)row*512 + lane*8;
    const float* q = ws2 + lane*8;
    float4 a0=*(const float4*)p, a1=*(const float4*)(p+4);
    float4 b0=*(const float4*)q, b1=*(const float4*)(q+4);
    float ssum = a0.x*b0.x + a0.y*b0.y + a0.z*b0.z + a0.w*b0.w
               + a1.x*b1.x + a1.y*b1.y + a1.z*b1.z + a1.w*b1.w;
#pragma unroll
    for (int m=1;m<64;m<<=1) ssum += __shfl_xor(ssum, m, 64);
    if (lane == 0){
        float z = ssum + bs2[0];
        float pr = 1.0f/(1.0f + __expf(-z));
        segp[row] = pr;
        dout[81920 + row] = pr;
    }
}

// ---------------------------------------------------------------------------
// Per-batch: mask scan (count, first-10 idx), pooled -> gctx
// ---------------------------------------------------------------------------
__global__ void select_gctx(float* __restrict__ ws_, const float* __restrict__ wgm,
                            const float* __restrict__ bgv)
{
    const float* h_hist = ws_ + OFF_HH;
    const float* segp   = ws_ + OFF_SEGP;
    float* gctx = ws_ + OFF_GCTX;
    int* sel = (int*)(ws_ + OFF_SEL);
    int b = blockIdx.x, tid = threadIdx.x;
    __shared__ unsigned char flag[1024];
    __shared__ float pool[1024];
    for (int j = tid; j < 1024; j += 256){
        flag[j] = segp[b*1024 + j] > 0.5f ? 1 : 0;
        pool[j] = (j < 512) ? h_hist[((size_t)1023*NB + b)*HD + j]
                            : h_hist[((size_t)T*NB + b)*HD + (j - 512)];
    }
    __syncthreads();
    if (tid == 0){
        int c = 0;
        int tmp[10];
        for (int j = 0; j < 10; ++j) tmp[j] = 0;
        for (int t = 0; t < 1024; ++t){
            if (flag[t]){ if (c < 10) tmp[c] = t; c++; }
        }
        for (int j = 0; j < 10; ++j) sel[b*12 + j] = tmp[j];
        sel[b*12 + 10] = c;
        sel[b*12 + 11] = 0;
    }
    __syncthreads();
    for (int n = tid; n < 1024; n += 256){
        float acc = bgv[n];
        const float* wr = wgm + (size_t)n*1024;
        for (int k = 0; k < 1024; k += 4){
            acc += wr[k]*pool[k] + wr[k+1]*pool[k+1] + wr[k+2]*pool[k+2] + wr[k+3]*pool[k+3];
        }
        gctx[b*1024 + n] = acc;
    }
}

// ---------------------------------------------------------------------------
// Decoder: one block per (b,slot)
// ---------------------------------------------------------------------------
__global__ void decode(const float* __restrict__ ws_, const float* __restrict__ wd1,
                       const float* __restrict__ bd1, const float* __restrict__ wd2,
                       const float* __restrict__ bd2, float* __restrict__ dout)
{
    const float* h_hist = ws_ + OFF_HH;
    const float* gctx   = ws_ + OFF_GCTX;
    const int* sel = (const int*)(ws_ + OFF_SEL);
    int blk = blockIdx.x;
    int b = blk / 10, slot = blk % 10;
    int tid = threadIdx.x;
    int count = sel[b*12 + 10];
    int nval = count < 10 ? count : 10;
    bool empty = (count == 0);
    float* outp = dout + (size_t)(b*10 + slot)*512;
    if (slot >= nval && !(empty && slot == 0)){
        for (int n = tid; n < 512; n += 256) outp[n] = 0.0f;
        return;
    }
    __shared__ float row[1024];
    __shared__ float dh[512];
    if (empty){
        for (int j = tid; j < 1024; j += 256) row[j] = gctx[b*1024 + j];
    } else {
        int t = sel[b*12 + slot];
        for (int j = tid; j < 1024; j += 256)
            row[j] = (j < 512) ? h_hist[((size_t)t*NB + b)*HD + j]
                               : h_hist[((size_t)(T + t)*NB + b)*HD + (j-512)];
    }
    __syncthreads();
    for (int d = tid; d < 512; d += 256){
        float acc = bd1[d];
        const float* wr = wd1 + (size_t)d*1024;
        for (int k = 0; k < 1024; ++k) acc += wr[k]*row[k];
        dh[d] = fmaxf(acc, 0.0f);
    }
    __syncthreads();
    for (int n = tid; n < 512; n += 256){
        float acc = bd2[n];
        const float* wr = wd2 + (size_t)n*512;
        for (int k = 0; k < 512; ++k) acc += wr[k]*dh[k];
        outp[n] = acc;
    }
}

extern "C" void kernel_launch(void* const* d_in, const int* in_sizes, int n_in,
                              void* d_out, int out_size, void* d_ws, size_t ws_size,
                              hipStream_t stream)
{
    const int*   instr = (const int*)d_in[0];
    const float* emb   = (const float*)d_in[1];
    const float* wih_f = (const float*)d_in[2];
    const float* whh_f = (const float*)d_in[3];
    const float* bih_f = (const float*)d_in[4];
    const float* bhh_f = (const float*)d_in[5];
    const float* wih_b = (const float*)d_in[6];
    const float* whh_b = (const float*)d_in[7];
    const float* bih_b = (const float*)d_in[8];
    const float* bhh_b = (const float*)d_in[9];
    const float* wg_   = (const float*)d_in[10];
    const float* bg_   = (const float*)d_in[11];
    const float* ws1   = (const float*)d_in[12];
    const float* bs1   = (const float*)d_in[13];
    const float* ws2   = (const float*)d_in[14];
    const float* bs2   = (const float*)d_in[15];
    const float* wd1   = (const float*)d_in[16];
    const float* bd1   = (const float*)d_in[17];
    const float* wd2   = (const float*)d_in[18];
    const float* bd2   = (const float*)d_in[19];
    float* out = (float*)d_out;
    float* ws  = (float*)d_ws;

    // zero the per-wg step flags (captured as a memset node; re-runs every replay)
    hipMemsetAsync(d_ws, 0, 2048, stream);

    hipLaunchKernelGGL(lstm_kernel, dim3(512), dim3(256), 0, stream,
                       instr, emb, wih_f, whh_f, bih_f, bhh_f,
                       wih_b, whh_b, bih_b, bhh_b, ws);
    hipLaunchKernelGGL(seg_gemm, dim3(256, 8), dim3(256), 0, stream, ws, ws1, bs1);
    hipLaunchKernelGGL(seg_score, dim3(4096), dim3(256), 0, stream, ws, ws2, bs2, out);
    hipLaunchKernelGGL(select_gctx, dim3(16), dim3(256), 0, stream, ws, wg_, bg_);
    hipLaunchKernelGGL(decode, dim3(160), dim3(256), 0, stream, ws, wd1, bd1, wd2, bd2, out);
}

// Round 16
// 4295.214 us; speedup vs baseline: 2.1857x; 1.0293x over previous
//
#include <hip/hip_runtime.h>
#include <math.h>

// Problem constants (fixed by reference)
#define T   1024
#define NB  16
#define HD  512

// ws layout (float offsets)
#define OFF_BAR  0                         // 512 ints: flag[2 dir][4 bgrp][64 uslice]
#define OFF_HH   768                       // h_hist [2][T][NB][HD] = 16,777,216 floats
#define OFF_SCR  (OFF_HH + 16777216)       // scores accumulator [16384]
#define OFF_SEGP (OFF_SCR + 16384)         // seg_probs [16384]
#define OFF_GCTX (OFF_SEGP + 16384)        // [16][1024]
#define OFF_SEL  (OFF_GCTX + 16384)        // ints [16][12]

typedef unsigned long long u64;

__device__ __forceinline__ float sigmoidf_(float x){ return 1.0f/(1.0f + __expf(-x)); }
// fast tanh via exp2-based __expf; |err| ~1e-7, graceful saturation at +/-1
__device__ __forceinline__ float tanhf_(float x){ return 1.0f - 2.0f/(1.0f + __expf(2.0f*x)); }

// ---------------------------------------------------------------------------
// Persistent bidirectional LSTM, TWO INDEPENDENT WGS PER CU (r15, best: 3.89ms).
// FROZEN: 9 structural variants (r4..r15) converge to the latency floor
// 1024 x (~1.3us compute + ~2.6us exposed cross-CU exchange) ~= 4ms.
// ---------------------------------------------------------------------------
__global__ __launch_bounds__(256, 2)
void lstm_kernel(const int* __restrict__ instr, const float* __restrict__ emb,
                 const float* __restrict__ wih_f, const float* __restrict__ whh_f,
                 const float* __restrict__ bih_f, const float* __restrict__ bhh_f,
                 const float* __restrict__ wih_b, const float* __restrict__ whh_b,
                 const float* __restrict__ bih_b, const float* __restrict__ bhh_b,
                 float* __restrict__ ws)
{
    float* h_hist = ws + OFF_HH;
    int* flags = (int*)ws;            // [2][4][64]

    const int wg     = blockIdx.x;    // 0..511
    const int dir    = wg >> 8;       // 0 = fwd (blocks 0..255), 1 = bwd
    const int rem    = wg & 255;
    const int bgrp   = rem & 3;       // batches bgrp*4..+3
    const int uslice = rem >> 2;      // 0..63
    const int U      = uslice * 8;    // 8 hidden units per wg
    const int b0     = bgrp * 4;

    int* barf = flags + (dir*4 + bgrp)*64;

    const float* wih = dir ? wih_b : wih_f;
    const float* whh = dir ? whh_b : whh_f;
    const float* bih = dir ? bih_b : bih_f;
    const float* bhh = dir ? bhh_b : bhh_f;

    const int tid  = threadIdx.x;
    const int wid  = tid >> 6;        // 0..3 = row-group
    const int lane = tid & 63;        // k-chunk id (8 k's per lane)

    // Weight slices: row rgl = wid*8+ri of 32 (gate = rgl>>3, ul = rgl&7)
    float wi[64], wh[64];
#pragma unroll
    for (int ri = 0; ri < 8; ++ri){
        int rgl = wid*8 + ri;
        int gate = rgl >> 3, ul = rgl & 7;
        size_t row = (size_t)(gate*HD + U + ul) * HD + lane*8;
        float4 a0 = *(const float4*)(wih + row);
        float4 a1 = *(const float4*)(wih + row + 4);
        float4 b0v = *(const float4*)(whh + row);
        float4 b1v = *(const float4*)(whh + row + 4);
        wi[ri*8+0]=a0.x; wi[ri*8+1]=a0.y; wi[ri*8+2]=a0.z; wi[ri*8+3]=a0.w;
        wi[ri*8+4]=a1.x; wi[ri*8+5]=a1.y; wi[ri*8+6]=a1.z; wi[ri*8+7]=a1.w;
        wh[ri*8+0]=b0v.x; wh[ri*8+1]=b0v.y; wh[ri*8+2]=b0v.z; wh[ri*8+3]=b0v.w;
        wh[ri*8+4]=b1v.x; wh[ri*8+5]=b1v.y; wh[ri*8+6]=b1v.z; wh[ri*8+7]=b1v.w;
    }

    // Gate biases: wave0 lane M (<32) owns (b = b0+(M>>3), unit = U+(M&7))
    float bI, bF, bG, bO, cst = 0.0f;
    {
        int u = tid & 7;
        bI = bih[0*HD + U + u] + bhh[0*HD + U + u];
        bF = bih[1*HD + U + u] + bhh[1*HD + U + u];
        bG = bih[2*HD + U + u] + bhh[2*HD + U + u];
        bO = bih[3*HD + U + u] + bhh[3*HD + U + u];
    }

    __shared__ float gbuf[128];       // [gate][bi*8 + ul]

    // reduce-scatter ownership (32 values, 5 xor stages + cross-half merge):
    const int jown = ((lane&1)<<4)|((lane&2)<<2)|(lane&4)|((lane&8)>>2)|((lane&16)>>4);
    const int own_bi  = jown >> 3;            // 0..3
    const int own_rgl = wid*8 + (jown & 7);   // 0..31
    const int gslot   = (own_rgl >> 3)*32 + own_bi*8 + (own_rgl & 7);

    for (int s = 0; s < T; ++s){
        const int tp = dir ? (T-1-s) : s;   // original-time index

        // ---- x gather + x-projection: independent of the recurrence
        float a[32];
#pragma unroll
        for (int j = 0; j < 32; ++j) a[j] = 0.0f;

#pragma unroll
        for (int bi = 0; bi < 4; ++bi){
            int b = b0 + bi;
            int idx = instr[b*T + tp];
            const float* px = emb + (size_t)idx*HD + lane*8;
            float4 x0 = *(const float4*)px;
            float4 x1 = *(const float4*)(px + 4);
            float xs[8] = {x0.x,x0.y,x0.z,x0.w,x1.x,x1.y,x1.z,x1.w};
#pragma unroll
            for (int kk = 0; kk < 8; ++kk){
                float xv = xs[kk];
#pragma unroll
                for (int ri = 0; ri < 8; ++ri)
                    a[bi*8+ri] = fmaf(xv, wi[ri*8+kk], a[bi*8+ri]);
            }
        }

        // ---- wait for step s-1 of the 64 wgs in this (dir,bgrp) domain
        if (s > 0){
            if (wid == 0){
                for (;;){
                    int v = __hip_atomic_load(barf + lane, __ATOMIC_RELAXED, __HIP_MEMORY_SCOPE_AGENT);
                    if (__all(v >= s)) break;
                    __builtin_amdgcn_s_sleep(1);
                }
            }
            __syncthreads();

            // ---- h-projection: plain cached loads (fresh address per step)
            const int tprev = dir ? (T - s) : (s - 1);
            const float* hbase = h_hist + (size_t)(dir*T + tprev)*NB*HD;
#pragma unroll
            for (int bi = 0; bi < 4; ++bi){
                const float* ph = hbase + (size_t)(b0+bi)*HD + lane*8;
                float4 h0 = *(const float4*)ph;
                float4 h1 = *(const float4*)(ph + 4);
                float hs[8] = {h0.x,h0.y,h0.z,h0.w,h1.x,h1.y,h1.z,h1.w};
#pragma unroll
                for (int kk = 0; kk < 8; ++kk){
                    float hv = hs[kk];
#pragma unroll
                    for (int ri = 0; ri < 8; ++ri)
                        a[bi*8+ri] = fmaf(hv, wh[ri*8+kk], a[bi*8+ri]);
                }
            }
        }

        // ---- reduce-scatter: 32 values over 64 lanes (5 stages + merge)
#pragma unroll
        for (int m = 0; m < 5; ++m){
            const int half = 16 >> m;
            const bool up = (lane >> m) & 1;
#pragma unroll
            for (int j = 0; j < 16; ++j){
                if (j < half){
                    float lo = a[j], hi = a[j+half];
                    float rlo = __shfl_xor(lo, 1<<m, 64);
                    float rhi = __shfl_xor(hi, 1<<m, 64);
                    a[j] = up ? (hi + rhi) : (lo + rlo);
                }
            }
        }
        a[0] += __shfl_xor(a[0], 32, 64);   // cross-half k merge

        if ((lane & 32) == 0) gbuf[gslot] = a[0];
        __syncthreads();

        if (tid < 32){   // wave-uniform branch: wave0 only
            float iv = sigmoidf_(gbuf[      tid] + bI);
            float fv = sigmoidf_(gbuf[ 32 + tid] + bF);
            float gv = tanhf_  (gbuf[ 64 + tid] + bG);
            float ov = sigmoidf_(gbuf[ 96 + tid] + bO);
            cst = fv*cst + iv*gv;
            float hv = ov * tanhf_(cst);
            int b = b0 + (tid >> 3), u = tid & 7;
            __hip_atomic_store(&h_hist[((size_t)(dir*T + tp)*NB + b)*HD + U + u], hv,
                               __ATOMIC_RELAXED, __HIP_MEMORY_SCOPE_AGENT);
        }
        asm volatile("s_waitcnt vmcnt(0)" ::: "memory");
        __builtin_amdgcn_sched_barrier(0);
        if (tid == 0)
            __hip_atomic_store(barf + uslice, s + 1, __ATOMIC_RELAXED, __HIP_MEMORY_SCOPE_AGENT);
    }
}

// ---------------------------------------------------------------------------
// FUSED seg head: scores[m] += sum_n relu(enc[m]·ws1[n] + bs1[n]) * ws2[n]
// M=16384, N=512, K=1024. 64x64 tiles, k-major LDS (vector ds_read_b128).
// SH is never materialized (saves 66MB of traffic + one kernel).
// ---------------------------------------------------------------------------
__global__ __launch_bounds__(256, 2)
void seg_gemm(const float* __restrict__ ws_, const float* __restrict__ ws1,
              const float* __restrict__ bs1, const float* __restrict__ ws2)
{
    const float* h_hist = ws_ + OFF_HH;
    float* scores = (float*)(ws_ + OFF_SCR);
    __shared__ float As[16][68];      // [k][m] transposed: vector reads
    __shared__ float Bs[16][68];      // [k][n]
    const int m0 = blockIdx.x * 64;
    const int n0 = blockIdx.y * 64;
    const int tid = threadIdx.x;
    const int r  = tid >> 2;          // 0..63
    const int kq = (tid & 3) * 4;
    const int ty = tid >> 4, tx = tid & 15;
    const int bI = m0 >> 10;          // tile stays inside one batch
    const int t0 = m0 & 1023;

    float acc[4][4];
#pragma unroll
    for (int i=0;i<4;i++)
#pragma unroll
        for (int j=0;j<4;j++) acc[i][j]=0.0f;

    for (int kb = 0; kb < 1024; kb += 16){
        int kk = kb + kq;
        const float* ap = (kk < 512)
            ? h_hist + ((size_t)(t0 + r)*NB + bI)*HD + kk
            : h_hist + ((size_t)(T + t0 + r)*NB + bI)*HD + (kk - 512);
        float4 av = *(const float4*)ap;
        As[kq+0][r]=av.x; As[kq+1][r]=av.y; As[kq+2][r]=av.z; As[kq+3][r]=av.w;
        float4 bv = *(const float4*)(ws1 + (size_t)(n0 + r)*1024 + kk);
        Bs[kq+0][r]=bv.x; Bs[kq+1][r]=bv.y; Bs[kq+2][r]=bv.z; Bs[kq+3][r]=bv.w;
        __syncthreads();
#pragma unroll
        for (int k2 = 0; k2 < 16; ++k2){
            float4 av_ = *(const float4*)&As[k2][ty*4];
            float4 bv_ = *(const float4*)&Bs[k2][tx*4];
            float am[4] = {av_.x, av_.y, av_.z, av_.w};
            float bn[4] = {bv_.x, bv_.y, bv_.z, bv_.w};
#pragma unroll
            for (int i=0;i<4;i++)
#pragma unroll
                for (int j=0;j<4;j++) acc[i][j] = fmaf(am[i], bn[j], acc[i][j]);
        }
        __syncthreads();
    }

    // fused epilogue: relu + ws2-weighted reduction over this block's 64 n's
    float b1[4], w2[4];
#pragma unroll
    for (int j=0;j<4;j++){
        int n = n0 + tx*4 + j;
        b1[j] = bs1[n];
        w2[j] = ws2[n];
    }
#pragma unroll
    for (int i=0;i<4;i++){
        float partial = 0.0f;
#pragma unroll
        for (int j=0;j<4;j++)
            partial += fmaxf(acc[i][j] + b1[j], 0.0f) * w2[j];
        // reduce over tx (16 lanes of same ty within the wave)
#pragma unroll
        for (int mm = 1; mm < 16; mm <<= 1)
            partial += __shfl_xor(partial, mm, 64);
        if (tx == 0)
            atomicAdd(&scores[m0 + ty*4 + i], partial);
    }
}

// ---------------------------------------------------------------------------
// finalize: seg_probs = sigmoid(scores + bs2) -> segp (ws) + d_out
// ---------------------------------------------------------------------------
__global__ void seg_final(float* __restrict__ ws_, const float* __restrict__ bs2,
                          float* __restrict__ dout)
{
    const float* scores = ws_ + OFF_SCR;
    float* segp = ws_ + OFF_SEGP;
    int m = blockIdx.x*256 + threadIdx.x;
    float pr = 1.0f/(1.0f + __expf(-(scores[m] + bs2[0])));
    segp[m] = pr;
    dout[81920 + m] = pr;
}

// ---------------------------------------------------------------------------
// Per-batch: mask scan (count, first-10 idx), pooled -> gctx
// ---------------------------------------------------------------------------
__global__ void select_gctx(float* __restrict__ ws_, const float* __restrict__ wgm,
                            const float* __restrict__ bgv)
{
    const float* h_hist = ws_ + OFF_HH;
    const float* segp   = ws_ + OFF_SEGP;
    float* gctx = ws_ + OFF_GCTX;
    int* sel = (int*)(ws_ + OFF_SEL);
    int b = blockIdx.x, tid = threadIdx.x;
    __shared__ unsigned char flag[1024];
    __shared__ float pool[1024];
    for (int j = tid; j < 1024; j += 256){
        flag[j] = segp[b*1024 + j] > 0.5f ? 1 : 0;
        pool[j] = (j < 512) ? h_hist[((size_t)1023*NB + b)*HD + j]
                            : h_hist[((size_t)T*NB + b)*HD + (j - 512)];
    }
    __syncthreads();
    if (tid == 0){
        int c = 0;
        int tmp[10];
        for (int j = 0; j < 10; ++j) tmp[j] = 0;
        for (int t = 0; t < 1024; ++t){
            if (flag[t]){ if (c < 10) tmp[c] = t; c++; }
        }
        for (int j = 0; j < 10; ++j) sel[b*12 + j] = tmp[j];
        sel[b*12 + 10] = c;
        sel[b*12 + 11] = 0;
    }
    __syncthreads();
    for (int n = tid; n < 1024; n += 256){
        float acc = bgv[n];
        const float* wr = wgm + (size_t)n*1024;
        for (int k = 0; k < 1024; k += 4){
            acc += wr[k]*pool[k] + wr[k+1]*pool[k+1] + wr[k+2]*pool[k+2] + wr[k+3]*pool[k+3];
        }
        gctx[b*1024 + n] = acc;
    }
}

// ---------------------------------------------------------------------------
// Decoder: one block per (b,slot)
// ---------------------------------------------------------------------------
__global__ void decode(const float* __restrict__ ws_, const float* __restrict__ wd1,
                       const float* __restrict__ bd1, const float* __restrict__ wd2,
                       const float* __restrict__ bd2, float* __restrict__ dout)
{
    const float* h_hist = ws_ + OFF_HH;
    const float* gctx   = ws_ + OFF_GCTX;
    const int* sel = (const int*)(ws_ + OFF_SEL);
    int blk = blockIdx.x;
    int b = blk / 10, slot = blk % 10;
    int tid = threadIdx.x;
    int count = sel[b*12 + 10];
    int nval = count < 10 ? count : 10;
    bool empty = (count == 0);
    float* outp = dout + (size_t)(b*10 + slot)*512;
    if (slot >= nval && !(empty && slot == 0)){
        for (int n = tid; n < 512; n += 256) outp[n] = 0.0f;
        return;
    }
    __shared__ float row[1024];
    __shared__ float dh[512];
    if (empty){
        for (int j = tid; j < 1024; j += 256) row[j] = gctx[b*1024 + j];
    } else {
        int t = sel[b*12 + slot];
        for (int j = tid; j < 1024; j += 256)
            row[j] = (j < 512) ? h_hist[((size_t)t*NB + b)*HD + j]
                               : h_hist[((size_t)(T + t)*NB + b)*HD + (j-512)];
    }
    __syncthreads();
    for (int d = tid; d < 512; d += 256){
        float acc = bd1[d];
        const float* wr = wd1 + (size_t)d*1024;
        for (int k = 0; k < 1024; ++k) acc += wr[k]*row[k];
        dh[d] = fmaxf(acc, 0.0f);
    }
    __syncthreads();
    for (int n = tid; n < 512; n += 256){
        float acc = bd2[n];
        const float* wr = wd2 + (size_t)n*512;
        for (int k = 0; k < 512; ++k) acc += wr[k]*dh[k];
        outp[n] = acc;
    }
}

extern "C" void kernel_launch(void* const* d_in, const int* in_sizes, int n_in,
                              void* d_out, int out_size, void* d_ws, size_t ws_size,
                              hipStream_t stream)
{
    const int*   instr = (const int*)d_in[0];
    const float* emb   = (const float*)d_in[1];
    const float* wih_f = (const float*)d_in[2];
    const float* whh_f = (const float*)d_in[3];
    const float* bih_f = (const float*)d_in[4];
    const float* bhh_f = (const float*)d_in[5];
    const float* wih_b = (const float*)d_in[6];
    const float* whh_b = (const float*)d_in[7];
    const float* bih_b = (const float*)d_in[8];
    const float* bhh_b = (const float*)d_in[9];
    const float* wg_   = (const float*)d_in[10];
    const float* bg_   = (const float*)d_in[11];
    const float* ws1   = (const float*)d_in[12];
    const float* bs1   = (const float*)d_in[13];
    const float* ws2   = (const float*)d_in[14];
    const float* bs2   = (const float*)d_in[15];
    const float* wd1   = (const float*)d_in[16];
    const float* bd1   = (const float*)d_in[17];
    const float* wd2   = (const float*)d_in[18];
    const float* bd2   = (const float*)d_in[19];
    float* out = (float*)d_out;
    float* ws  = (float*)d_ws;

    // zero the per-wg step flags + the fused-score accumulator (every replay)
    hipMemsetAsync(d_ws, 0, 2048, stream);
    hipMemsetAsync((char*)d_ws + (size_t)OFF_SCR*4, 0, 16384*4, stream);

    hipLaunchKernelGGL(lstm_kernel, dim3(512), dim3(256), 0, stream,
                       instr, emb, wih_f, whh_f, bih_f, bhh_f,
                       wih_b, whh_b, bih_b, bhh_b, ws);
    hipLaunchKernelGGL(seg_gemm, dim3(256, 8), dim3(256), 0, stream, ws, ws1, bs1, ws2);
    hipLaunchKernelGGL(seg_final, dim3(64), dim3(256), 0, stream, ws, bs2, out);
    hipLaunchKernelGGL(select_gctx, dim3(16), dim3(256), 0, stream, ws, wg_, bg_);
    hipLaunchKernelGGL(decode, dim3(160), dim3(256), 0, stream, ws, wd1, bd1, wd2, bd2, out);
}